// Round 5
// baseline (561.365 us; speedup 1.0000x reference)
//
#include <hip/hip_runtime.h>
#include <hip/hip_cooperative_groups.h>

namespace cg = cooperative_groups;

#define MIN_VAL 1e-8f
#define SENT    1e10f   // invalid-target sentinel: d ~ 1e20 dominates any valid d
#define ACCINIT 1e30f

constexpr int P     = 256;   // bins per sample (bins input is [N, P+1])
constexpr int BLOCK = 256;
constexpr int CHUNK = 512;   // targets per block-iteration

// ws layout (computed dynamically in kernel_launch):
//   done     : 1 unsigned  (init by block 0 BEFORE grid.sync -> race-free)
//   res      : N doubles   (per-sample cham_x+cham_y, written in phase 2)
//   ysum_part: N*CPS doubles  (plain stores, phase 1)
//   ycnt_part: N*CPS unsigned
//   binpart  : N*CPS*P floats (per-block per-bin partial mins, plain stores)

__global__ void __launch_bounds__(BLOCK, 4)
chamfer_coop(const float* __restrict__ bins, const float* __restrict__ tgt,
             int N, int M, int CPS, int C,
             unsigned* done, double* res, double* ysum_part,
             unsigned* ycnt_part, float* binpart, float* out) {
    const int bid = blockIdx.x;
    const int n   = bid / CPS;      // sample
    const int s   = bid % CPS;      // chunk-slice within sample
    const int tid = threadIdx.x;
    const int tg  = tid & 15;       // target-slot lane within 16-group
    const int bg  = tid >> 4;       // bin-group: bins [bg*16, bg*16+16)
    const int w   = tid >> 6;       // wave 0..3 (covers bins [w*64, w*64+64))
    const int lane = tid & 63;

    __shared__ float  s_bc[P];
    __shared__ float  s_t[CHUNK];
    __shared__ float  s_colw[4][CHUNK];   // per-wave col-min partials
    __shared__ float  s_binmin[P];
    __shared__ double s_red[8];
    __shared__ unsigned s_redc[4];

    if (bid == 0 && tid == 0) *done = 0u;   // visible after grid.sync

    // ---- stage bin centers -------------------------------------------------
    const float* bn = bins + (size_t)n * (P + 1);
    s_bc[tid] = 0.5f * (bn[tid] + bn[tid + 1]);
    __syncthreads();
    float bcv[16];
#pragma unroll
    for (int i = 0; i < 16; i += 4) {
        float4 v = *(const float4*)&s_bc[bg * 16 + i];
        bcv[i] = v.x; bcv[i + 1] = v.y; bcv[i + 2] = v.z; bcv[i + 3] = v.w;
    }
    float rmin[16];
#pragma unroll
    for (int i = 0; i < 16; ++i) rmin[i] = ACCINIT;

    double ylocal = 0.0;
    unsigned ycl = 0;
    const float* tp = tgt + (size_t)n * M;

    // ---- phase 1: strided chunks (CPS=128 -> exactly one per block) --------
    for (int c = s; c < C; c += CPS) {
        const int m0 = c * CHUNK;
        float ta = (m0 + tid < M)       ? tp[m0 + tid]       : -1.0f;
        float tb = (m0 + tid + 256 < M) ? tp[m0 + tid + 256] : -1.0f;
        bool va = ta >= MIN_VAL, vb = tb >= MIN_VAL;
        __syncthreads();               // s_t / s_colw reuse guard
        s_t[tid]       = va ? ta : SENT;
        s_t[tid + 256] = vb ? tb : SENT;
        __syncthreads();

        // 4 passes of 16 bins x 8 targets, next-pass targets preloaded
        float4 na = *(const float4*)&s_t[tg * 8];
        float4 nb = *(const float4*)&s_t[tg * 8 + 4];
#pragma unroll 1
        for (int pass = 0; pass < 4; ++pass) {
            float tv[8] = {na.x, na.y, na.z, na.w, nb.x, nb.y, nb.z, nb.w};
            if (pass < 3) {
                na = *(const float4*)&s_t[(pass + 1) * 128 + tg * 8];
                nb = *(const float4*)&s_t[(pass + 1) * 128 + tg * 8 + 4];
            }
            float cmin[8];
#pragma unroll
            for (int j = 0; j < 8; ++j) cmin[j] = ACCINIT;
#pragma unroll
            for (int j = 0; j < 8; ++j) {
                float t = tv[j];
                float cm = cmin[j];
#pragma unroll
                for (int i = 0; i < 16; ++i) {
                    float d = bcv[i] - t;
                    d = d * d;
                    rmin[i] = fminf(rmin[i], d);
                    cm = fminf(cm, d);
                }
                cmin[j] = cm;
            }
            // combine the wave's 4 bin-groups: lanes {l, l^16, l^32, l^48}
#pragma unroll
            for (int j = 0; j < 8; ++j) {
                float cm = cmin[j];
                cm = fminf(cm, __shfl_xor(cm, 16, 64));
                cm = fminf(cm, __shfl_xor(cm, 32, 64));
                cmin[j] = cm;
            }
            if ((tid & 48) == 0) {    // lanes 0-15 of each wave
                float* cp = &s_colw[w][pass * 128 + tg * 8];
                *(float4*)cp       = make_float4(cmin[0], cmin[1], cmin[2], cmin[3]);
                *(float4*)(cp + 4) = make_float4(cmin[4], cmin[5], cmin[6], cmin[7]);
            }
        }
        __syncthreads();

        // per-target min over all 256 bins (4 wave-partials)
        float c0 = fminf(fminf(s_colw[0][tid], s_colw[1][tid]),
                         fminf(s_colw[2][tid], s_colw[3][tid]));
        float c1 = fminf(fminf(s_colw[0][tid + 256], s_colw[1][tid + 256]),
                         fminf(s_colw[2][tid + 256], s_colw[3][tid + 256]));
        ylocal += (va ? (double)c0 : 0.0) + (vb ? (double)c1 : 0.0);
        ycl    += (unsigned)va + (unsigned)vb;
    }

    // ---- per-bin mins -> s_binmin ------------------------------------------
#pragma unroll
    for (int i = 0; i < 16; ++i) {
        float r = rmin[i];
        r = fminf(r, __shfl_down(r, 8, 16));
        r = fminf(r, __shfl_down(r, 4, 16));
        r = fminf(r, __shfl_down(r, 2, 16));
        r = fminf(r, __shfl_down(r, 1, 16));
        rmin[i] = r;
    }
    if (tg == 0) {
#pragma unroll
        for (int i = 0; i < 16; i += 4)
            *(float4*)&s_binmin[bg * 16 + i] =
                make_float4(rmin[i], rmin[i + 1], rmin[i + 2], rmin[i + 3]);
    }

    // ---- block-reduce cham_y partials --------------------------------------
    for (int off = 32; off > 0; off >>= 1) {
        ylocal += __shfl_down(ylocal, off, 64);
        ycl    += __shfl_down(ycl, off, 64);
    }
    if (lane == 0) { s_red[w] = ylocal; s_redc[w] = ycl; }
    __syncthreads();

    // ---- plain coalesced stores of this block's partials -------------------
    binpart[((size_t)n * CPS + s) * P + tid] = s_binmin[tid];
    if (tid == 0) {
        ysum_part[n * CPS + s] = s_red[0] + s_red[1] + s_red[2] + s_red[3];
        ycnt_part[n * CPS + s] = s_redc[0] + s_redc[1] + s_redc[2] + s_redc[3];
    }

    cg::this_grid().sync();

    // ---- phase 2: 8 blocks reduce partials ---------------------------------
    if (bid < N) {
        const int nn = bid;
        float acc = ACCINIT;
        const float* bp = binpart + (size_t)nn * CPS * P + tid;
#pragma unroll 4
        for (int cc = 0; cc < CPS; ++cc) acc = fminf(acc, bp[(size_t)cc * P]);
        double sx = (double)acc;
        double sy = 0.0; unsigned cnt = 0;
        for (int i = tid; i < CPS; i += BLOCK) {
            sy  += ysum_part[nn * CPS + i];
            cnt += ycnt_part[nn * CPS + i];
        }
        for (int off = 32; off > 0; off >>= 1) {
            sx  += __shfl_down(sx, off, 64);
            sy  += __shfl_down(sy, off, 64);
            cnt += __shfl_down(cnt, off, 64);
        }
        __syncthreads();   // s_red reuse guard
        if (lane == 0) { s_red[w] = sx; s_red[4 + w] = sy; s_redc[w] = cnt; }
        __syncthreads();
        if (tid == 0) {
            double SX = (s_red[0] + s_red[1] + s_red[2] + s_red[3]) / (double)P;
            double SYs = s_red[4] + s_red[5] + s_red[6] + s_red[7];
            unsigned CC = s_redc[0] + s_redc[1] + s_redc[2] + s_redc[3];
            res[nn] = SX + SYs / (double)CC;
            __threadfence();
            unsigned old = __hip_atomic_fetch_add(done, 1u, __ATOMIC_ACQ_REL,
                                                  __HIP_MEMORY_SCOPE_AGENT);
            if (old == (unsigned)(N - 1)) {   // last sample-block finalizes
                double tot = 0.0;
                for (int k = 0; k < N; ++k)
                    tot += __hip_atomic_load(&res[k], __ATOMIC_RELAXED,
                                             __HIP_MEMORY_SCOPE_AGENT);
                out[0] = (float)(tot / (double)N);
            }
        }
    }
}

extern "C" void kernel_launch(void* const* d_in, const int* in_sizes, int n_in,
                              void* d_out, int out_size, void* d_ws, size_t ws_size,
                              hipStream_t stream) {
    const float* bins = (const float*)d_in[0];
    const float* tgt  = (const float*)d_in[1];
    float* out = (float*)d_out;

    const int N = in_sizes[0] / (P + 1);      // 8
    const int M = in_sizes[1] / N;            // 65536
    const int C = (M + CHUNK - 1) / CHUNK;    // 128 total chunks per sample

    // cooperative residency bound
    int numCU = 256, maxb = 4;
    hipDeviceProp_t prop;
    if (hipGetDeviceProperties(&prop, 0) == hipSuccess) numCU = prop.multiProcessorCount;
    (void)hipOccupancyMaxActiveBlocksPerMultiprocessor(&maxb, (const void*)chamfer_coop,
                                                       BLOCK, 0);
    if (maxb < 1) maxb = 1;

    // pick CPS: fits in ws AND grid co-resident
    int CPS = (C < 128) ? C : 128;
    size_t o_done, o_res, o_ys, o_yc, o_bp, need;
    for (;;) {
        o_done = 0;
        o_res  = 64;
        o_ys   = ((o_res + (size_t)N * 8 + 63) / 64) * 64;
        o_yc   = o_ys + (size_t)N * CPS * 8;
        o_bp   = ((o_yc + (size_t)N * CPS * 4 + 15) / 16) * 16;
        need   = o_bp + (size_t)N * CPS * P * 4;
        if ((need <= ws_size && (size_t)N * CPS <= (size_t)maxb * numCU) || CPS == 1)
            break;
        CPS >>= 1;
    }

    char* ws = (char*)d_ws;
    unsigned* done    = (unsigned*)(ws + o_done);
    double*   res     = (double*)(ws + o_res);
    double*   ysum_p  = (double*)(ws + o_ys);
    unsigned* ycnt_p  = (unsigned*)(ws + o_yc);
    float*    binpart = (float*)(ws + o_bp);

    int Nn = N, Mm = M, CPSv = CPS, Cv = C;
    void* args[] = {(void*)&bins, (void*)&tgt, (void*)&Nn, (void*)&Mm,
                    (void*)&CPSv, (void*)&Cv, (void*)&done, (void*)&res,
                    (void*)&ysum_p, (void*)&ycnt_p, (void*)&binpart, (void*)&out};
    hipLaunchCooperativeKernel((void*)chamfer_coop, dim3(N * CPS), dim3(BLOCK),
                               args, 0, stream);
}